// Round 3
// baseline (144.786 us; speedup 1.0000x reference)
//
#include <hip/hip_runtime.h>
#include <hip/hip_bf16.h>

using f32x4   = __attribute__((ext_vector_type(4))) float;
using short8  = __attribute__((ext_vector_type(8))) short;
using short4v = __attribute__((ext_vector_type(4))) short;

#define LOG_2PI 1.8378770664093453f
#define HP2 640   // padded phoneme axis: 640 halves = 1280B row stride (128B-aligned)

__device__ __forceinline__ short bf16bits(float x) {
  unsigned u = __builtin_bit_cast(unsigned, x);
  u = (u + 0x7FFFu + ((u >> 16) & 1u)) >> 16;   // RNE; inputs are finite
  return (short)u;
}
__device__ __forceinline__ float bf16round(float x) {
  unsigned u = __builtin_bit_cast(unsigned, x);
  u = ((u + 0x7FFFu + ((u >> 16) & 1u)) >> 16) << 16;
  return __builtin_bit_cast(float, u);
}

// Kernel 0: per (b,h) Gaussian params: center c, q = 0.5/var, base = -0.5*(log2pi+log var)
__global__ void prep_kernel(const float* __restrict__ dur,
                            const float* __restrict__ vars,
                            float* __restrict__ cA, float* __restrict__ qA,
                            float* __restrict__ bA, int H) {
  const int b = blockIdx.x;
  const int l = threadIdx.x;
  float run = 0.f;
  for (int h0 = 0; h0 < H; h0 += 64) {
    const int h = h0 + l;
    const float d = (h < H) ? dur[(size_t)b * H + h] : 0.f;
    float x = d;
#pragma unroll
    for (int off = 1; off < 64; off <<= 1) {
      float y = __shfl_up(x, off);
      if (l >= off) x += y;
    }
    if (h < H) {
      const float v = vars[(size_t)b * H + h];
      cA[(size_t)b * H + h] = run + x - 0.5f * d;
      qA[(size_t)b * H + h] = 0.5f / v;
      bA[(size_t)b * H + h] = -0.5f * (LOG_2PI + logf(v));
    }
    run += __shfl(x, 63);
  }
}

// Kernel 1: enc [B][H][D] f32 -> encT [B][D][HP2] bf16 (h >= H zero-padded).
__global__ void transpose_kernel(const float* __restrict__ enc,
                                 short* __restrict__ encT,
                                 int H, int D) {
  __shared__ short sT[64][66];
  const int b  = blockIdx.z;
  const int h0 = blockIdx.y * 64;
  const int d0 = blockIdx.x * 64;
  const int tid = threadIdx.x;
  const int tx = tid & 63;         // d within tile
  const int ty = tid >> 6;         // 0..3

  const float* ebase = enc + (size_t)b * H * D + d0 + tx;
#pragma unroll
  for (int i = 0; i < 16; ++i) {
    const int h = h0 + ty + i * 4;
    const float v = (h < H) ? ebase[(size_t)h * D] : 0.f;
    sT[tx][ty + i * 4] = bf16bits(v);
  }
  __syncthreads();

  const int tx4 = (tid & 15) * 4;  // h within tile (4 consecutive)
  const int ty2 = tid >> 4;        // 0..15 (d)
#pragma unroll
  for (int i = 0; i < 4; ++i) {
    const int d = d0 + ty2 + i * 16;
    short4v v;
#pragma unroll
    for (int j = 0; j < 4; ++j) v[j] = sT[ty2 + i * 16][tx4 + j];
    *(short4v*)&encT[((size_t)b * D + d) * HP2 + h0 + tx4] = v;
  }
}

// Main fused kernel. Block tile = 128 frames x 256 d-cols (8 waves as 2m x 4d,
// each wave a 64x64 sub-tile). 1D grid, XCD-swizzled so that all blocks of a
// batch run on one XCD (encT[b] slice stays L2-resident: 4 batches x 622KB).
__launch_bounds__(512, 1)
__global__ void gup_kernel(const short* __restrict__ encT,
                           const float* __restrict__ cA,
                           const float* __restrict__ qA,
                           const float* __restrict__ bA,
                           const int* __restrict__ lens,
                           float* __restrict__ out,
                           int H, int T, int TT, int DD, int nwg) {
  constexpr int D  = 512;
  constexpr int AS = 40;           // sA row stride in halves (80B)

  __shared__ float sc[HP2], sq[HP2], sb[HP2];
  __shared__ float sden[128];
  __shared__ short sA[2][128 * AS];

  // bijective XCD swizzle (m204 variant): consecutive lin -> same XCD
  const int orig = blockIdx.x;
  const int q8 = nwg >> 3, r8 = nwg & 7, xcd = orig & 7;
  const int lin = (xcd < r8 ? xcd * (q8 + 1) : r8 * (q8 + 1) + (xcd - r8) * q8)
                + (orig >> 3);
  const int b   = lin / (TT * DD);
  const int rem = lin - b * (TT * DD);
  const int dd  = rem / TT;
  const int tt  = rem - dd * TT;
  const int t0    = tt * 128;
  const int dbase = dd * 256;

  const int tid = threadIdx.x;
  const int L   = lens[b];

  // phase 0: params -> LDS (zero-padded to HP2)
  for (int i = tid; i < HP2; i += 512) {
    const bool ok = i < H;
    sc[i] = ok ? cA[(size_t)b * H + i] : 0.f;
    sq[i] = ok ? qA[(size_t)b * H + i] : 0.f;
    sb[i] = ok ? bA[(size_t)b * H + i] : 0.f;
  }
  __syncthreads();

  // phase 1: per-frame max score over valid h (4 lanes per frame).
  // After the xor-reduce every lane holds its frame's max; the thread->frame
  // map is identical to the A-build map, so no LDS round-trip needed.
  const int tfA = tid >> 2;                 // frame 0..127
  const int hs  = tid & 3;
  const float tA = (float)(t0 + tfA);
  float mA = -1e30f;
  for (int h = hs; h < L; h += 4) {
    const float d = tA - sc[h];
    mA = fmaxf(mA, fmaf(-d * d, sq[h], sb[h]));
  }
  mA = fmaxf(mA, __shfl_xor(mA, 1));
  mA = fmaxf(mA, __shfl_xor(mA, 2));

  const int lane = tid & 63;
  const int wv   = tid >> 6;
  const int wr   = wv >> 2;                 // 0..1 (m-half)
  const int wc   = wv & 3;                  // 0..3 (d-quarter)
  const int l15  = lane & 15;
  const int lq   = lane >> 4;

  f32x4 acc[4][4];
#pragma unroll
  for (int i = 0; i < 4; ++i)
#pragma unroll
    for (int j = 0; j < 4; ++j) acc[i][j] = (f32x4){0.f, 0.f, 0.f, 0.f};

  const int k8 = (tid & 3) * 8;             // this thread's 8 k-slots in sA
  float denAcc = 0.f;

  // this lane's B-fragment base: row d = dbase + wc*64 + l15, col chunk + lq*8
  const short* bp = encT + ((size_t)b * D + dbase + wc * 64 + l15) * HP2 + lq * 8;

  const int nChunks = (L + 31) >> 5;
  int p = 0;

  for (int cc = 0; cc < nChunks; ++cc, p ^= 1) {
    const int h0 = cc * 32;

    // A tile: unnormalized weights w = exp(score - m), bf16 (RNE)
    {
      short8 w;
#pragma unroll
      for (int j = 0; j < 8; ++j) {
        const int h = h0 + k8 + j;
        const float d = tA - sc[h];
        const float s = fmaf(-d * d, sq[h], sb[h]);
        float pv = __expf(s - mA);
        pv = (h < L) ? pv : 0.f;
        w[j] = bf16bits(pv);
        denAcc += bf16round(pv);
      }
      *(short8*)&sA[p][tfA * AS + k8] = w;
    }
    __syncthreads();

    short8 af[4], bf[4];
#pragma unroll
    for (int mt = 0; mt < 4; ++mt)
      af[mt] = *(short8*)&sA[p][(wr * 64 + mt * 16 + l15) * AS + lq * 8];
#pragma unroll
    for (int nt = 0; nt < 4; ++nt)
      bf[nt] = *(const short8*)(bp + (size_t)nt * 16 * HP2 + h0);
#pragma unroll
    for (int mt = 0; mt < 4; ++mt)
#pragma unroll
      for (int nt = 0; nt < 4; ++nt)
        acc[mt][nt] = __builtin_amdgcn_mfma_f32_16x16x32_bf16(af[mt], bf[nt], acc[mt][nt], 0, 0, 0);
    // single barrier per chunk: next iteration writes the other sA buffer.
  }

  // denominators: reduce the 4 threads sharing a frame
  {
    float dsum = denAcc;
    dsum += __shfl_xor(dsum, 1);
    dsum += __shfl_xor(dsum, 2);
    if ((tid & 3) == 0) sden[tfA] = dsum;
  }
  __syncthreads();

  // epilogue: normalize and store
#pragma unroll
  for (int mt = 0; mt < 4; ++mt) {
#pragma unroll
    for (int i = 0; i < 4; ++i) {
      const int tr = wr * 64 + mt * 16 + lq * 4 + i;
      const int tg = t0 + tr;
      if (tg < T) {
        const float inv = 1.0f / sden[tr];
#pragma unroll
        for (int nt = 0; nt < 4; ++nt) {
          const int dc = dbase + wc * 64 + nt * 16 + l15;
          out[((size_t)b * T + tg) * D + dc] = acc[mt][nt][i] * inv;
        }
      }
    }
  }
}

extern "C" void kernel_launch(void* const* d_in, const int* in_sizes, int n_in,
                              void* d_out, int out_size, void* d_ws, size_t ws_size,
                              hipStream_t stream) {
  const float* enc  = (const float*)d_in[0];
  const float* dur  = (const float*)d_in[1];
  const float* vars = (const float*)d_in[2];
  const int*   lens = (const int*)d_in[3];

  const int B = in_sizes[3];
  const int H = in_sizes[1] / B;
  const int D = in_sizes[0] / in_sizes[1];
  const int T = out_size / (B * D);
  (void)n_in; (void)ws_size;

  float* cA = (float*)d_ws;
  float* qA = cA + (size_t)B * H;
  float* bA = qA + (size_t)B * H;
  short* encT = (short*)(bA + (size_t)B * H);   // B*D*HP2 bf16 ~= 21 MB

  prep_kernel<<<B, 64, 0, stream>>>(dur, vars, cA, qA, bA, H);

  dim3 tgrid(D / 64, HP2 / 64, B);
  transpose_kernel<<<tgrid, 256, 0, stream>>>(enc, encT, H, D);

  const int TT  = (T + 127) / 128;
  const int DD  = D / 256;
  const int nwg = TT * DD * B;
  gup_kernel<<<nwg, 512, 0, stream>>>(encT, cA, qA, bA, lens, (float*)d_out,
                                      H, T, TT, DD, nwg);
}

// Round 4
// 91.665 us; speedup vs baseline: 1.5795x; 1.5795x over previous
//
#include <hip/hip_runtime.h>
#include <hip/hip_bf16.h>

using f32x4   = __attribute__((ext_vector_type(4))) float;
using short8  = __attribute__((ext_vector_type(8))) short;
using short4v = __attribute__((ext_vector_type(4))) short;

#define LOG_2PI 1.8378770664093453f
#define HP2 640   // padded phoneme axis (640 halves = 1280B rows, 128B-aligned)

__device__ __forceinline__ short bf16bits(float x) {
  unsigned u = __builtin_bit_cast(unsigned, x);
  u = (u + 0x7FFFu + ((u >> 16) & 1u)) >> 16;   // RNE; inputs are finite
  return (short)u;
}
__device__ __forceinline__ float bf16round(float x) {
  unsigned u = __builtin_bit_cast(unsigned, x);
  u = ((u + 0x7FFFu + ((u >> 16) & 1u)) >> 16) << 16;
  return __builtin_bit_cast(float, u);
}

// Kernel 0: per (b,h) Gaussian params + per-batch window-bound reductions.
// aux[b*8+..] = {Gmax, qMin, qMax, bMin, bMax} over VALID h (< L).
__global__ void prep_kernel(const float* __restrict__ dur,
                            const float* __restrict__ vars,
                            const int* __restrict__ lens,
                            float* __restrict__ cA, float* __restrict__ qA,
                            float* __restrict__ bA, float* __restrict__ aux,
                            int H) {
  const int b = blockIdx.x;
  const int l = threadIdx.x;
  const int L = lens[b];
  float run = 0.f, prevD = 0.f;
  float Gmax = 0.f, qMin = 1e30f, qMax = 0.f, bMin = 1e30f, bMax = -1e30f;
  for (int h0 = 0; h0 < H; h0 += 64) {
    const int h = h0 + l;
    const float d = (h < H) ? dur[(size_t)b * H + h] : 0.f;
    float x = d;
#pragma unroll
    for (int off = 1; off < 64; off <<= 1) {
      float y = __shfl_up(x, off);
      if (l >= off) x += y;
    }
    float dp = __shfl_up(d, 1);
    if (l == 0) dp = prevD;
    if (h < H) {
      const float v = vars[(size_t)b * H + h];
      const float q = 0.5f / v;
      const float bc = -0.5f * (LOG_2PI + logf(v));
      cA[(size_t)b * H + h] = run + x - 0.5f * d;
      qA[(size_t)b * H + h] = q;
      bA[(size_t)b * H + h] = bc;
      if (h < L) {
        qMin = fminf(qMin, q); qMax = fmaxf(qMax, q);
        bMin = fminf(bMin, bc); bMax = fmaxf(bMax, bc);
        if (h >= 1) Gmax = fmaxf(Gmax, 0.5f * (d + dp));  // center gap
      }
    }
    prevD = __shfl(d, 63);
    run += __shfl(x, 63);
  }
#pragma unroll
  for (int off = 1; off < 64; off <<= 1) {
    qMin = fminf(qMin, __shfl_xor(qMin, off));
    qMax = fmaxf(qMax, __shfl_xor(qMax, off));
    bMin = fminf(bMin, __shfl_xor(bMin, off));
    bMax = fmaxf(bMax, __shfl_xor(bMax, off));
    Gmax = fmaxf(Gmax, __shfl_xor(Gmax, off));
  }
  if (l == 0) {
    float* ax = aux + b * 8;
    ax[0] = Gmax; ax[1] = qMin; ax[2] = qMax; ax[3] = bMin; ax[4] = bMax;
  }
}

// Kernel 1: enc [B][H][D] f32 -> encT [B][D][HP2] bf16 (h >= H zero-padded).
__global__ void transpose_kernel(const float* __restrict__ enc,
                                 short* __restrict__ encT,
                                 int H, int D) {
  __shared__ short sT[64][66];
  const int b  = blockIdx.z;
  const int h0 = blockIdx.y * 64;
  const int d0 = blockIdx.x * 64;
  const int tid = threadIdx.x;
  const int tx = tid & 63;
  const int ty = tid >> 6;

  const float* ebase = enc + (size_t)b * H * D + d0 + tx;
#pragma unroll
  for (int i = 0; i < 16; ++i) {
    const int h = h0 + ty + i * 4;
    const float v = (h < H) ? ebase[(size_t)h * D] : 0.f;
    sT[tx][ty + i * 4] = bf16bits(v);
  }
  __syncthreads();

  const int tx4 = (tid & 15) * 4;
  const int ty2 = tid >> 4;
#pragma unroll
  for (int i = 0; i < 4; ++i) {
    const int d = d0 + ty2 + i * 16;
    short4v v;
#pragma unroll
    for (int j = 0; j < 4; ++j) v[j] = sT[ty2 + i * 16][tx4 + j];
    *(short4v*)&encT[((size_t)b * D + d) * HP2 + h0 + tx4] = v;
  }
}

// Main fused kernel: block = (64-frame tile, batch). 512 threads = 8 waves,
// wave w owns d in [64w, 64w+64). Chunk-windowed: only K-chunks whose centers
// fall within W of the tile are processed (others contribute < e^-45 relative).
__launch_bounds__(512, 1)
__global__ void gup_kernel(const short* __restrict__ encT,
                           const float* __restrict__ cA,
                           const float* __restrict__ qA,
                           const float* __restrict__ bA,
                           const float* __restrict__ aux,
                           const int* __restrict__ lens,
                           float* __restrict__ out,
                           int H, int T) {
  constexpr int D  = 512;
  constexpr int AS = 40;           // sA row stride in halves (80B)

  __shared__ __align__(16) float sc[HP2], sq[HP2], sb[HP2];
  __shared__ float sden[64];
  __shared__ short sA[2][64 * AS];

  const int tid = threadIdx.x;
  const int b   = blockIdx.y;
  const int t0  = blockIdx.x * 64;
  const int L   = lens[b];

  // phase 0: params -> LDS. sb = -1e30 for h >= L => scores auto-masked.
  for (int i = tid; i < HP2; i += 512) {
    const bool okH = i < H;
    sc[i] = okH ? cA[(size_t)b * H + i] : 0.f;
    sq[i] = okH ? qA[(size_t)b * H + i] : 0.f;
    sb[i] = (i < L) ? bA[(size_t)b * H + i] : -1e30f;
  }
  __syncthreads();

  // window bound: drop h iff guaranteed score < per-frame max - 45
  const float Gmax = aux[b * 8 + 0], qMn = aux[b * 8 + 1], qMx = aux[b * 8 + 2];
  const float bMn  = aux[b * 8 + 3], bMx = aux[b * 8 + 4];
  const float tLo = (float)t0;
  const float tHi = (float)(min(t0 + 63, T - 1));
  const float c0 = sc[0], cL = sc[L - 1];
  const float D0 = fmaxf(0.5f * Gmax, fmaxf(fmaxf(c0 - tLo, tHi - cL), 0.f));
  const float Wr = __fsqrt_rn(((bMx - bMn) + 45.f + qMx * D0 * D0) / qMn);

  // binary search window [hLo, hHi) in monotone centers (broadcast LDS reads)
  int lo = 0, hi = L;
  const float thLo = tLo - Wr;
  while (lo < hi) { const int mid = (lo + hi) >> 1; if (sc[mid] < thLo) lo = mid + 1; else hi = mid; }
  int hLo = lo;
  int lo2 = hLo, hi2 = L;
  const float thHi = tHi + Wr;
  while (lo2 < hi2) { const int mid = (lo2 + hi2) >> 1; if (sc[mid] <= thHi) lo2 = mid + 1; else hi2 = mid; }
  int hHi = lo2;
  if (hHi <= hLo) { hLo = max(hLo - 1, 0); hHi = min(hLo + 2, L); }  // paranoia
  const int cLo = hLo >> 5;
  const int cHi = (hHi + 31) >> 5;

  // premax: exact per-frame max over the window (8 lanes/frame, float4 reads)
  const int tfA = tid >> 3;
  const int hs8 = tid & 7;
  const float tA = (float)(t0 + tfA);
  float mA = -1e30f;
  for (int h4 = cLo * 32 + hs8 * 4; h4 < cHi * 32; h4 += 32) {
    const f32x4 cv = *(const f32x4*)&sc[h4];
    const f32x4 qv = *(const f32x4*)&sq[h4];
    const f32x4 bv = *(const f32x4*)&sb[h4];
#pragma unroll
    for (int j = 0; j < 4; ++j) {
      const float dd = tA - cv[j];
      mA = fmaxf(mA, fmaf(-dd * dd, qv[j], bv[j]));
    }
  }
  mA = fmaxf(mA, __shfl_xor(mA, 1));
  mA = fmaxf(mA, __shfl_xor(mA, 2));
  mA = fmaxf(mA, __shfl_xor(mA, 4));

  const int lane = tid & 63;
  const int wv   = tid >> 6;
  const int l15  = lane & 15;
  const int lq   = lane >> 4;

  f32x4 acc[4][4];
#pragma unroll
  for (int i = 0; i < 4; ++i)
#pragma unroll
    for (int j = 0; j < 4; ++j) acc[i][j] = (f32x4){0.f, 0.f, 0.f, 0.f};

  float denAcc = 0.f;
  const short* bp = encT + ((size_t)b * D + wv * 64 + l15) * HP2 + lq * 8;

  int p = 0;
  for (int cc = cLo; cc < cHi; ++cc, p ^= 1) {
    const int h0 = cc * 32;

    // prefetch B-fragments (global, L2-resident) before the A-build VALU
    short8 bfv[4];
#pragma unroll
    for (int nt = 0; nt < 4; ++nt)
      bfv[nt] = *(const short8*)(bp + (size_t)nt * 16 * HP2 + h0);

    // A tile: unnormalized weights w = exp(score - m), bf16 (RNE)
    {
      const int hb = h0 + hs8 * 4;
      const f32x4 cv = *(const f32x4*)&sc[hb];
      const f32x4 qv = *(const f32x4*)&sq[hb];
      const f32x4 bv = *(const f32x4*)&sb[hb];
      short4v w;
#pragma unroll
      for (int j = 0; j < 4; ++j) {
        const float dd = tA - cv[j];
        const float s = fmaf(-dd * dd, qv[j], bv[j]);
        const float pv = __expf(s - mA);
        w[j] = bf16bits(pv);
        denAcc += bf16round(pv);
      }
      *(short4v*)&sA[p][tfA * AS + hs8 * 4] = w;
    }
    __syncthreads();

    short8 af[4];
#pragma unroll
    for (int mt = 0; mt < 4; ++mt)
      af[mt] = *(short8*)&sA[p][(mt * 16 + l15) * AS + lq * 8];
    // swapped operands: acc[mt][nt] holds C[d][t] -> lane gets 4 consecutive d
#pragma unroll
    for (int mt = 0; mt < 4; ++mt)
#pragma unroll
      for (int nt = 0; nt < 4; ++nt)
        acc[mt][nt] = __builtin_amdgcn_mfma_f32_16x16x32_bf16(bfv[nt], af[mt], acc[mt][nt], 0, 0, 0);
    // single barrier per chunk: next iteration writes the other sA buffer.
  }

  // denominators: reduce the 8 threads sharing a frame
  {
    float dsum = denAcc;
    dsum += __shfl_xor(dsum, 1);
    dsum += __shfl_xor(dsum, 2);
    dsum += __shfl_xor(dsum, 4);
    if (hs8 == 0) sden[tfA] = dsum;
  }
  __syncthreads();

  // epilogue: normalize and store float4 (4 consecutive d per thread)
#pragma unroll
  for (int mt = 0; mt < 4; ++mt) {
    const int tg = t0 + mt * 16 + l15;
    const float inv = 1.0f / sden[mt * 16 + l15];
    if (tg < T) {
#pragma unroll
      for (int nt = 0; nt < 4; ++nt) {
        f32x4 o;
#pragma unroll
        for (int i = 0; i < 4; ++i) o[i] = acc[mt][nt][i] * inv;
        *(f32x4*)&out[((size_t)b * T + tg) * D + wv * 64 + nt * 16 + lq * 4] = o;
      }
    }
  }
}

extern "C" void kernel_launch(void* const* d_in, const int* in_sizes, int n_in,
                              void* d_out, int out_size, void* d_ws, size_t ws_size,
                              hipStream_t stream) {
  const float* enc  = (const float*)d_in[0];
  const float* dur  = (const float*)d_in[1];
  const float* vars = (const float*)d_in[2];
  const int*   lens = (const int*)d_in[3];

  const int B = in_sizes[3];
  const int H = in_sizes[1] / B;
  const int D = in_sizes[0] / in_sizes[1];
  const int T = out_size / (B * D);
  (void)n_in; (void)ws_size;

  float* cA  = (float*)d_ws;
  float* qA  = cA + (size_t)B * H;
  float* bA  = qA + (size_t)B * H;
  float* aux = bA + (size_t)B * H;
  short* encT = (short*)(aux + 8 * (size_t)B);   // B*D*HP2 bf16 ~= 21 MB

  prep_kernel<<<B, 64, 0, stream>>>(dur, vars, lens, cA, qA, bA, aux, H);

  dim3 tgrid(D / 64, HP2 / 64, B);
  transpose_kernel<<<tgrid, 256, 0, stream>>>(enc, encT, H, D);

  dim3 grid((T + 63) / 64, B);
  gup_kernel<<<grid, 512, 0, stream>>>(encT, cA, qA, bA, aux, lens,
                                       (float*)d_out, H, T);
}